// Round 10
// baseline (182.472 us; speedup 1.0000x reference)
//
#include <hip/hip_runtime.h>
#include <hip/hip_bf16.h>
#include <math.h>

#define NHEADS 16
#define DHEAD  64
#define CHDIM  80
#define RQn    6
#define RKn    2
#define RVn    2
#define BB     2
#define TT     2048
#define DDim   1024
#define NQK    800   // 480 + 320 combined projection rows

using frag16 = __attribute__((ext_vector_type(8))) short;   // 8 bf16 (4 VGPR)
using f32x4  = __attribute__((ext_vector_type(4))) float;   // 4 fp32 acc
using f32x16 = __attribute__((ext_vector_type(16))) float;  // 32x32 acc
using uint2v = __attribute__((ext_vector_type(2))) unsigned int;

#define AS1(p) ((const __attribute__((address_space(1))) unsigned int*)(p))
#define AS3(p) ((__attribute__((address_space(3))) unsigned int*)(p))

static __device__ __forceinline__ unsigned short bf16_bits(float f) {
    __hip_bfloat16 h = __float2bfloat16(f);
    return *(unsigned short*)&h;
}
static __device__ __forceinline__ unsigned int pk2(float a, float b) {
    return ((unsigned int)bf16_bits(b) << 16) | (unsigned int)bf16_bits(a);
}
static __device__ __forceinline__ float bfu2f(unsigned short u) {
    return __uint_as_float(((unsigned int)u) << 16);
}
// HW exp2 via the proper intrinsic (hazard-safe). log2(e) folded into q-scale.
static __device__ __forceinline__ float exp2_hw(float x) {
    return __builtin_amdgcn_exp2f(x);
}

// ---------------- fused fp32 -> bf16 convert (4 segments, 1 launch) ----------
__global__ __launch_bounds__(256) void cvt_all(
    const float* __restrict__ x, const float* __restrict__ wq,
    const float* __restrict__ wk, const float* __restrict__ wo,
    __hip_bfloat16* __restrict__ xb, __hip_bfloat16* __restrict__ wqk,
    __hip_bfloat16* __restrict__ wob)
{
    int bid = blockIdx.x;
    const float* src; __hip_bfloat16* dst; int n4;
    if (bid < 4096)      { src = x;  dst = xb;            n4 = 1048576; }
    else if (bid < 4576) { bid -= 4096; src = wq; dst = wqk;           n4 = 122880; }
    else if (bid < 4896) { bid -= 4576; src = wk; dst = wqk + 491520;  n4 = 81920; }
    else                 { bid -= 4896; src = wo; dst = wob;           n4 = 262144; }
    int i = bid * 256 + threadIdx.x;
    if (i < n4) {
        float4 v = *(const float4*)&src[i * 4];
        ushort4 o;
        o.x = bf16_bits(v.x); o.y = bf16_bits(v.y);
        o.z = bf16_bits(v.z); o.w = bf16_bits(v.w);
        *(ushort4*)&dst[i * 4] = o;
    }
}

// ---------- GEMM: C[M,N] = A[M,K]_bf16 * W[N,K]_bf16^T, 64x128 tile ---------
// BF16OUT: write bf16 C (used for abqkv to halve the round-trip traffic).
template <bool BF16OUT>
__global__ __launch_bounds__(256) void gemm_bf16(
    const __hip_bfloat16* __restrict__ A, const __hip_bfloat16* __restrict__ W,
    void* __restrict__ Cv, int M, int N, int K)
{
    __shared__ __hip_bfloat16 Asl[2][64 * 64];
    __shared__ __hip_bfloat16 Bsl[2][128 * 64];
    const int tid = threadIdx.x;
    const int w = tid >> 6, lane = tid & 63;
    const int l16 = lane & 15, quad = lane >> 4;
    const int bm = blockIdx.y * 64, bn = blockIdx.x * 128;

    // staging geometry
    int rSA[2], cSA[2];
    #pragma unroll
    for (int j = 0; j < 2; j++) {
        int L = (w * 2 + j) * 64 + lane;
        rSA[j] = L >> 3;
        cSA[j] = (L & 7) ^ (rSA[j] & 7);
    }
    int rSB[4], cSB[4];
    #pragma unroll
    for (int j = 0; j < 4; j++) {
        int L = (w * 4 + j) * 64 + lane;
        int r = L >> 3;
        cSB[j] = (L & 7) ^ (r & 7);
        int rb = bn + r;
        rSB[j] = (rb < N) ? rb : (N - 1);
    }

    f32x4 acc[4][2];
    #pragma unroll
    for (int mt = 0; mt < 4; mt++)
        #pragma unroll
        for (int nt = 0; nt < 2; nt++)
            acc[mt][nt] = (f32x4){0.f, 0.f, 0.f, 0.f};

    const int nK = K >> 6;
    #pragma unroll
    for (int j = 0; j < 2; j++)
        __builtin_amdgcn_global_load_lds(AS1(A + (size_t)(bm + rSA[j]) * K + cSA[j] * 8),
                                         AS3(&Asl[0][(w * 2 + j) * 512]), 16, 0, 0);
    #pragma unroll
    for (int j = 0; j < 4; j++)
        __builtin_amdgcn_global_load_lds(AS1(W + (size_t)rSB[j] * K + cSB[j] * 8),
                                         AS3(&Bsl[0][(w * 4 + j) * 512]), 16, 0, 0);

    for (int kk = 0; kk < nK; kk++) {
        const int cur = kk & 1;
        __syncthreads();
        if (kk + 1 < nK) {
            const int k1 = (kk + 1) * 64;
            #pragma unroll
            for (int j = 0; j < 2; j++)
                __builtin_amdgcn_global_load_lds(AS1(A + (size_t)(bm + rSA[j]) * K + k1 + cSA[j] * 8),
                                                 AS3(&Asl[cur ^ 1][(w * 2 + j) * 512]), 16, 0, 0);
            #pragma unroll
            for (int j = 0; j < 4; j++)
                __builtin_amdgcn_global_load_lds(AS1(W + (size_t)rSB[j] * K + k1 + cSB[j] * 8),
                                                 AS3(&Bsl[cur ^ 1][(w * 4 + j) * 512]), 16, 0, 0);
        }
        #pragma unroll
        for (int ks = 0; ks < 2; ks++) {
            frag16 af[4], bf[2];
            #pragma unroll
            for (int mt = 0; mt < 4; mt++) {
                int r = mt * 16 + l16;
                af[mt] = *(const frag16*)&Asl[cur][r * 64 + (((ks * 4 + quad) ^ (r & 7)) * 8)];
            }
            #pragma unroll
            for (int nt = 0; nt < 2; nt++) {
                int r = w * 32 + nt * 16 + l16;
                bf[nt] = *(const frag16*)&Bsl[cur][r * 64 + (((ks * 4 + quad) ^ (r & 7)) * 8)];
            }
            #pragma unroll
            for (int mt = 0; mt < 4; mt++)
                #pragma unroll
                for (int nt = 0; nt < 2; nt++)
                    acc[mt][nt] = __builtin_amdgcn_mfma_f32_16x16x32_bf16(af[mt], bf[nt], acc[mt][nt], 0, 0, 0);
        }
    }
    #pragma unroll
    for (int mt = 0; mt < 4; mt++) {
        #pragma unroll
        for (int reg = 0; reg < 4; reg++) {
            int row = bm + mt * 16 + quad * 4 + reg;
            #pragma unroll
            for (int nt = 0; nt < 2; nt++) {
                int col = bn + w * 32 + nt * 16 + l16;
                if (col < N) {
                    if constexpr (BF16OUT)
                        ((__hip_bfloat16*)Cv)[(size_t)row * N + col] = __float2bfloat16(acc[mt][nt][reg]);
                    else
                        ((float*)Cv)[(size_t)row * N + col] = acc[mt][nt][reg];
                }
            }
        }
    }
}

// ---------------- RoPE + rank contraction, 4 tokens/block ----------
// Reads bf16 abqkv (packed 2xbf16 = 4B/lane loads), stages fp32 in LDS.
__global__ __launch_bounds__(256) void qkv_kernel(
    const __hip_bfloat16* __restrict__ ab,
    __hip_bfloat16* __restrict__ q, __hip_bfloat16* __restrict__ k,
    __hip_bfloat16* __restrict__ vT)
{
    const int tok0 = blockIdx.x * 4;
    const int w = threadIdx.x >> 6;
    const int d = threadIdx.x & 63;
    const int token = tok0 + w;
    const int b = token / TT;
    const int t = token % TT;
    __shared__ float sab[4][NQK];
    __shared__ __align__(8) __hip_bfloat16 vbuf[NHEADS][DHEAD][4];
    const __hip_bfloat16* aq = ab + (size_t)token * NQK;
    #pragma unroll
    for (int i2 = d; i2 < NQK / 2; i2 += 64) {
        unsigned int u = *(const unsigned int*)&aq[i2 * 2];
        sab[w][i2 * 2 + 0] = bfu2f((unsigned short)(u & 0xffff));
        sab[w][i2 * 2 + 1] = bfu2f((unsigned short)(u >> 16));
    }
    const float* sq  = sab[w];
    const float* skv = sab[w] + 480;
    const int i32 = d & 31;
    // 10000^(-i/32) = 2^(-i/32 * log2(10000))
    float inv_freq = exp2_hw(-(float)i32 * (13.287712379549449f / 32.0f));
    float fr = (float)t * inv_freq;
    float c = cosf(fr), s = sinf(fr);
    __syncthreads();
    float rot[4];
    #pragma unroll
    for (int r = 0; r < 4; r++) {
        float x1 = skv[r * CHDIM + NHEADS + i32];
        float x2 = skv[r * CHDIM + NHEADS + 32 + i32];
        rot[r] = (d < 32) ? (x1 * c + x2 * s) : (-x1 * s + x2 * c);
    }
    float bqv[RQn];
    #pragma unroll
    for (int r = 0; r < RQn; r++) bqv[r] = sq[r * CHDIM + NHEADS + d];
    #pragma unroll
    for (int h = 0; h < NHEADS; h++) {
        float accq = 0.0f;
        #pragma unroll
        for (int r = 0; r < RQn; r++)
            accq += sq[r * CHDIM + h] * bqv[r];
        // q-scale: 1/sqrt(64)/RQ with log2(e) folded in (flash uses 2^x).
        q[((size_t)(b * NHEADS + h) * TT + t) * DHEAD + d] =
            __float2bfloat16(accq * (0.125f / 6.0f) * 1.4426950408889634f);
        float acck = 0.0f, accv = 0.0f;
        #pragma unroll
        for (int r = 0; r < RKn; r++)
            acck += skv[r * CHDIM + h] * rot[r];
        #pragma unroll
        for (int r = 0; r < RVn; r++)
            accv += skv[(RKn + r) * CHDIM + h] * rot[RKn + r];
        k[((size_t)(b * NHEADS + h) * TT + t) * DHEAD + d] = __float2bfloat16(acck * 0.5f);
        vbuf[h][d][w] = __float2bfloat16(accv * 0.5f);
    }
    __syncthreads();
    const int t0 = tok0 % TT;
    const int b0 = tok0 / TT;
    for (int row = threadIdx.x; row < NHEADS * DHEAD; row += 256) {
        int h = row >> 6, dd = row & 63;
        *(uint2*)&vT[((size_t)(b0 * NHEADS + h) * DHEAD + dd) * TT + t0] =
            *(const uint2*)&vbuf[h][dd][0];
    }
}

// -------- P^T B-frag construction from exp'd S registers (shared helper) ----
// __builtin_amdgcn_permlane32_swap(A,B,fi,bc) -> {A',B'} where
//   A' = {A.lo lanes 0-31, B.lo delivered to lanes 32-63}
//   B' = {A.hi delivered to lanes 0-31, B.hi lanes 32-63}
static __device__ __forceinline__ void build_pfrag(
    const float* s0, const float* s1, frag16 Pf[4])
{
    #pragma unroll
    for (int k2 = 0; k2 < 4; k2++) {
        const float* sF = (k2 >= 2) ? s1 : s0;
        const int bs = 8 * (k2 & 1);
        unsigned int a0 = pk2(sF[bs + 0], sF[bs + 1]);
        unsigned int b0 = pk2(sF[bs + 2], sF[bs + 3]);
        unsigned int a1 = pk2(sF[bs + 4], sF[bs + 5]);
        unsigned int b1 = pk2(sF[bs + 6], sF[bs + 7]);
        uint2v ra = __builtin_amdgcn_permlane32_swap(a0, a1, false, false);
        uint2v rb = __builtin_amdgcn_permlane32_swap(b0, b1, false, false);
        union { frag16 f; unsigned int u[4]; } pf;
        pf.u[0] = ra[0]; pf.u[1] = rb[0]; pf.u[2] = ra[1]; pf.u[3] = rb[1];
        Pf[k2] = pf.f;
    }
}

// ---------------- single attention tile (LDS operands, XOR-swizzled) --------
static __device__ __forceinline__ void attn_tile(
    const __hip_bfloat16* __restrict__ Kc, const __hip_bfloat16* __restrict__ Vc,
    const frag16 qB[4], f32x16& O0, f32x16& O1, float& lpart,
    const int l31, const int hi, const int xi,
    const bool domask, const int kb0, const int qlane)
{
    f32x16 ST0 = {}, ST1 = {};
    __builtin_amdgcn_s_setprio(1);
    #pragma unroll
    for (int kt4 = 0; kt4 < 4; kt4++) {
        int c8 = kt4 * 2 + hi;
        frag16 kf0 = *(const frag16*)&Kc[l31 * 64 + ((c8 ^ xi) * 8)];
        frag16 kf1 = *(const frag16*)&Kc[(32 + l31) * 64 + ((c8 ^ xi) * 8)];
        ST0 = __builtin_amdgcn_mfma_f32_32x32x16_bf16(kf0, qB[kt4], ST0, 0, 0, 0);
        ST1 = __builtin_amdgcn_mfma_f32_32x32x16_bf16(kf1, qB[kt4], ST1, 0, 0, 0);
    }
    __builtin_amdgcn_s_setprio(0);
    float* s0 = (float*)&ST0;
    float* s1 = (float*)&ST1;
    if (domask) {
        int kbq = kb0 + 4 * hi;
        #pragma unroll
        for (int reg = 0; reg < 16; reg++) {
            int rowc = (reg & 3) + 8 * (reg >> 2);
            if (kbq + rowc > qlane)      s0[reg] = -1e30f;
            if (kbq + 32 + rowc > qlane) s1[reg] = -1e30f;
        }
    }
    #pragma unroll
    for (int reg = 0; reg < 16; reg++) {
        float p0 = exp2_hw(s0[reg]);
        float p1 = exp2_hw(s1[reg]);
        s0[reg] = p0; s1[reg] = p1;
        lpart += p0 + p1;
    }
    frag16 Pf[4];
    build_pfrag(s0, s1, Pf);
    __builtin_amdgcn_s_setprio(1);
    #pragma unroll
    for (int k2 = 0; k2 < 4; k2++) {
        int c8 = k2 * 2 + hi;
        frag16 vf0 = *(const frag16*)&Vc[l31 * 64 + ((c8 ^ xi) * 8)];
        frag16 vf1 = *(const frag16*)&Vc[(32 + l31) * 64 + ((c8 ^ xi) * 8)];
        O0 = __builtin_amdgcn_mfma_f32_32x32x16_bf16(vf0, Pf[k2], O0, 0, 0, 0);
        O1 = __builtin_amdgcn_mfma_f32_32x32x16_bf16(vf1, Pf[k2], O1, 0, 0, 0);
    }
    __builtin_amdgcn_s_setprio(0);
}

// ------- barrier-free causal flash attention, 2048 one-wave blocks ----------
// Block = one wave = (bh, qt, w): 32 q-rows, full K range [0, ktd]. The wave
// stages its OWN K/V tiles (8+8KB, dbuf = 32KB -> 5 blocks/CU) and syncs with
// counted `s_waitcnt vmcnt(16)` (T4: prev tile's 16 global_load_lds are the
// oldest in this wave's FIFO) + sched_barrier(0) (rule #18). No __syncthreads,
// no vmcnt(0) drains in the loop -> waves de-phase, pipes fill (fixes the R9
// convoy: all 8 waves phase-locked by per-step barriers, 58% stall).
// Coalescing preserved: same staged-LDS layout as R9 (R7 lesson).
// LPT dispatch: qt = 15 - qtIdx so longest blocks launch first.
// XCD pinning (T1): Bid&7 = XCD, 4 bh/XCD -> 2MB K/V set in 4MB L2.
__global__ __launch_bounds__(64) void flash_mfma(
    const __hip_bfloat16* __restrict__ q, const __hip_bfloat16* __restrict__ k,
    const __hip_bfloat16* __restrict__ vT, __hip_bfloat16* __restrict__ y)
{
    const int Bid = blockIdx.x;          // 2048
    const int xcd = Bid & 7;
    const int bhsub = (Bid >> 3) & 3;
    const int w = (Bid >> 5) & 3;
    const int qtIdx = (Bid >> 7) & 15;
    const int qt = 15 - qtIdx;           // descending: LPT
    const int bh = xcd * 4 + bhsub;

    const int lane = threadIdx.x;
    const int l31 = lane & 31;
    const int hi = lane >> 5;
    const int xi = l31 & 7;
    const int paddr = (lane ^ 32) << 2;

    __shared__ __align__(16) __hip_bfloat16 Ks[2][4096];
    __shared__ __align__(16) __hip_bfloat16 Vs[2][4096];

    const size_t base = (size_t)bh * TT * DHEAD;
    const __hip_bfloat16* qb = q + base;
    const __hip_bfloat16* kb = k + base;
    const __hip_bfloat16* vb = vT + base;

    const int ktd = 2 * qt + (w >> 1);           // this wave's diagonal tile
    const int nsteps = ktd + 1;
    const int qlane = qt * 128 + w * 32 + l31;   // this lane's q row

    // 8 K-loads + 8 V-loads per tile, all issued by this wave.
    int offK[8], offV[8];
    #pragma unroll
    for (int j = 0; j < 8; j++) {
        int L = j * 64 + lane;
        int r = L >> 3, c8 = L & 7, g8 = c8 ^ (r & 7);
        offK[j] = r * 64 + g8 * 8;
        offV[j] = r * TT + g8 * 8;
    }

    frag16 qB[4];
    #pragma unroll
    for (int kt4 = 0; kt4 < 4; kt4++)
        qB[kt4] = *(const frag16*)&qb[(size_t)qlane * DHEAD + kt4 * 16 + hi * 8];
    // retire qB loads so the staging FIFO arithmetic below is exact
    asm volatile("s_waitcnt vmcnt(0)" ::: "memory");

#define STAGE_TILE(PHYS, BUF)                                                          \
    _Pragma("unroll")                                                                  \
    for (int j = 0; j < 8; j++) {                                                      \
        __builtin_amdgcn_global_load_lds(AS1(kb + (size_t)(PHYS) * 4096 + offK[j]),    \
                                         AS3(&Ks[BUF][j * 512]), 16, 0, 0);            \
        __builtin_amdgcn_global_load_lds(AS1(vb + (size_t)(PHYS) * 64 + offV[j]),      \
                                         AS3(&Vs[BUF][j * 512]), 16, 0, 0);            \
    }

    f32x16 O0 = {}, O1 = {};
    float l = 0.0f;

    STAGE_TILE(0, 0);
    for (int phys = 0; phys < nsteps; phys++) {
        const int cur = phys & 1;
        if (phys + 1 < nsteps) {
            STAGE_TILE(phys + 1, cur ^ 1);
            // 32 outstanding; wait until <=16 -> tile `phys` (oldest 16) done
            asm volatile("s_waitcnt vmcnt(16)" ::: "memory");
        } else {
            asm volatile("s_waitcnt vmcnt(0)" ::: "memory");
        }
        __builtin_amdgcn_sched_barrier(0);
        attn_tile(Ks[cur], Vs[cur], qB, O0, O1, l,
                  l31, hi, xi, phys == ktd, phys * 64, qlane);
    }
#undef STAGE_TILE

    // epilogue: combine lane^32 l-partials, normalize, write y bf16
    float lother = __int_as_float(__builtin_amdgcn_ds_bpermute(paddr, __float_as_int(l)));
    float inv = 1.0f / (l + lother);
    float* o0 = (float*)&O0;
    float* o1 = (float*)&O1;
    const int b = bh >> 4, h = bh & 15;
    __hip_bfloat16* yp = y + ((size_t)(b * TT + qlane)) * DDim + h * DHEAD;
    #pragma unroll
    for (int gg = 0; gg < 4; gg++) {
        int d0 = 8 * gg + 4 * hi;
        uint2 pa, pb;
        pa.x = pk2(o0[4*gg+0] * inv, o0[4*gg+1] * inv);
        pa.y = pk2(o0[4*gg+2] * inv, o0[4*gg+3] * inv);
        pb.x = pk2(o1[4*gg+0] * inv, o1[4*gg+1] * inv);
        pb.y = pk2(o1[4*gg+2] * inv, o1[4*gg+3] * inv);
        *(uint2*)&yp[d0] = pa;
        *(uint2*)&yp[32 + d0] = pb;
    }
}

extern "C" void kernel_launch(void* const* d_in, const int* in_sizes, int n_in,
                              void* d_out, int out_size, void* d_ws, size_t ws_size,
                              hipStream_t stream) {
    const float* x      = (const float*)d_in[0];
    const float* W_abq  = (const float*)d_in[1];
    const float* W_abkv = (const float*)d_in[2];
    const float* W_o    = (const float*)d_in[3];
    float* out = (float*)d_out;

    char* ws = (char*)d_ws;
    __hip_bfloat16* xb   = (__hip_bfloat16*)ws;  ws += (size_t)4194304 * 2;
    __hip_bfloat16* wqk  = (__hip_bfloat16*)ws;  ws += (size_t)NQK * 1024 * 2;
    __hip_bfloat16* wo_b = (__hip_bfloat16*)ws;  ws += (size_t)1048576 * 2;
    __hip_bfloat16* abqkv = (__hip_bfloat16*)ws; ws += (size_t)4096 * NQK * 2;
    __hip_bfloat16* qb = (__hip_bfloat16*)ws;    ws += (size_t)4194304 * 2;
    __hip_bfloat16* kb = (__hip_bfloat16*)ws;    ws += (size_t)4194304 * 2;
    __hip_bfloat16* vT = (__hip_bfloat16*)ws;    ws += (size_t)4194304 * 2;
    __hip_bfloat16* yb = (__hip_bfloat16*)ws;    ws += (size_t)4194304 * 2;

    cvt_all<<<dim3(5920), dim3(256), 0, stream>>>(x, W_abq, W_abkv, W_o, xb, wqk, wo_b);
    gemm_bf16<true><<<dim3(7, 64), dim3(256), 0, stream>>>(xb, wqk, abqkv, 4096, NQK, 1024);
    qkv_kernel<<<dim3(1024), dim3(256), 0, stream>>>(abqkv, qb, kb, vT);
    flash_mfma<<<dim3(2048), dim3(64), 0, stream>>>(qb, kb, vT, yb);
    gemm_bf16<false><<<dim3(8, 64), dim3(256), 0, stream>>>(yb, wo_b, out, 4096, 1024, 1024);
}

// Round 11
// 160.793 us; speedup vs baseline: 1.1348x; 1.1348x over previous
//
#include <hip/hip_runtime.h>
#include <hip/hip_bf16.h>
#include <math.h>

#define NHEADS 16
#define DHEAD  64
#define CHDIM  80
#define RQn    6
#define RKn    2
#define RVn    2
#define BB     2
#define TT     2048
#define DDim   1024
#define NQK    800   // 480 + 320 combined projection rows

using frag16 = __attribute__((ext_vector_type(8))) short;   // 8 bf16 (4 VGPR)
using f32x4  = __attribute__((ext_vector_type(4))) float;   // 4 fp32 acc
using f32x16 = __attribute__((ext_vector_type(16))) float;  // 32x32 acc
using uint2v = __attribute__((ext_vector_type(2))) unsigned int;

#define AS1(p) ((const __attribute__((address_space(1))) unsigned int*)(p))
#define AS3(p) ((__attribute__((address_space(3))) unsigned int*)(p))

static __device__ __forceinline__ unsigned short bf16_bits(float f) {
    __hip_bfloat16 h = __float2bfloat16(f);
    return *(unsigned short*)&h;
}
static __device__ __forceinline__ unsigned int pk2(float a, float b) {
    return ((unsigned int)bf16_bits(b) << 16) | (unsigned int)bf16_bits(a);
}
static __device__ __forceinline__ float bfu2f(unsigned short u) {
    return __uint_as_float(((unsigned int)u) << 16);
}
// HW exp2 via the proper intrinsic (hazard-safe). log2(e) folded into q-scale.
static __device__ __forceinline__ float exp2_hw(float x) {
    return __builtin_amdgcn_exp2f(x);
}

// ---------------- fused fp32 -> bf16 convert (4 segments, 1 launch) ----------
__global__ __launch_bounds__(256) void cvt_all(
    const float* __restrict__ x, const float* __restrict__ wq,
    const float* __restrict__ wk, const float* __restrict__ wo,
    __hip_bfloat16* __restrict__ xb, __hip_bfloat16* __restrict__ wqk,
    __hip_bfloat16* __restrict__ wob)
{
    int bid = blockIdx.x;
    const float* src; __hip_bfloat16* dst; int n4;
    if (bid < 4096)      { src = x;  dst = xb;            n4 = 1048576; }
    else if (bid < 4576) { bid -= 4096; src = wq; dst = wqk;           n4 = 122880; }
    else if (bid < 4896) { bid -= 4576; src = wk; dst = wqk + 491520;  n4 = 81920; }
    else                 { bid -= 4896; src = wo; dst = wob;           n4 = 262144; }
    int i = bid * 256 + threadIdx.x;
    if (i < n4) {
        float4 v = *(const float4*)&src[i * 4];
        ushort4 o;
        o.x = bf16_bits(v.x); o.y = bf16_bits(v.y);
        o.z = bf16_bits(v.z); o.w = bf16_bits(v.w);
        *(ushort4*)&dst[i * 4] = o;
    }
}

// ---------- GEMM: C[M,N] = A[M,K]_bf16 * W[N,K]_bf16^T, 64x128 tile ---------
// BF16OUT: write bf16 C (used for abqkv to halve the round-trip traffic).
template <bool BF16OUT>
__global__ __launch_bounds__(256) void gemm_bf16(
    const __hip_bfloat16* __restrict__ A, const __hip_bfloat16* __restrict__ W,
    void* __restrict__ Cv, int M, int N, int K)
{
    __shared__ __hip_bfloat16 Asl[2][64 * 64];
    __shared__ __hip_bfloat16 Bsl[2][128 * 64];
    const int tid = threadIdx.x;
    const int w = tid >> 6, lane = tid & 63;
    const int l16 = lane & 15, quad = lane >> 4;
    const int bm = blockIdx.y * 64, bn = blockIdx.x * 128;

    // staging geometry
    int rSA[2], cSA[2];
    #pragma unroll
    for (int j = 0; j < 2; j++) {
        int L = (w * 2 + j) * 64 + lane;
        rSA[j] = L >> 3;
        cSA[j] = (L & 7) ^ (rSA[j] & 7);
    }
    int rSB[4], cSB[4];
    #pragma unroll
    for (int j = 0; j < 4; j++) {
        int L = (w * 4 + j) * 64 + lane;
        int r = L >> 3;
        cSB[j] = (L & 7) ^ (r & 7);
        int rb = bn + r;
        rSB[j] = (rb < N) ? rb : (N - 1);
    }

    f32x4 acc[4][2];
    #pragma unroll
    for (int mt = 0; mt < 4; mt++)
        #pragma unroll
        for (int nt = 0; nt < 2; nt++)
            acc[mt][nt] = (f32x4){0.f, 0.f, 0.f, 0.f};

    const int nK = K >> 6;
    #pragma unroll
    for (int j = 0; j < 2; j++)
        __builtin_amdgcn_global_load_lds(AS1(A + (size_t)(bm + rSA[j]) * K + cSA[j] * 8),
                                         AS3(&Asl[0][(w * 2 + j) * 512]), 16, 0, 0);
    #pragma unroll
    for (int j = 0; j < 4; j++)
        __builtin_amdgcn_global_load_lds(AS1(W + (size_t)rSB[j] * K + cSB[j] * 8),
                                         AS3(&Bsl[0][(w * 4 + j) * 512]), 16, 0, 0);

    for (int kk = 0; kk < nK; kk++) {
        const int cur = kk & 1;
        __syncthreads();
        if (kk + 1 < nK) {
            const int k1 = (kk + 1) * 64;
            #pragma unroll
            for (int j = 0; j < 2; j++)
                __builtin_amdgcn_global_load_lds(AS1(A + (size_t)(bm + rSA[j]) * K + k1 + cSA[j] * 8),
                                                 AS3(&Asl[cur ^ 1][(w * 2 + j) * 512]), 16, 0, 0);
            #pragma unroll
            for (int j = 0; j < 4; j++)
                __builtin_amdgcn_global_load_lds(AS1(W + (size_t)rSB[j] * K + k1 + cSB[j] * 8),
                                                 AS3(&Bsl[cur ^ 1][(w * 4 + j) * 512]), 16, 0, 0);
        }
        #pragma unroll
        for (int ks = 0; ks < 2; ks++) {
            frag16 af[4], bf[2];
            #pragma unroll
            for (int mt = 0; mt < 4; mt++) {
                int r = mt * 16 + l16;
                af[mt] = *(const frag16*)&Asl[cur][r * 64 + (((ks * 4 + quad) ^ (r & 7)) * 8)];
            }
            #pragma unroll
            for (int nt = 0; nt < 2; nt++) {
                int r = w * 32 + nt * 16 + l16;
                bf[nt] = *(const frag16*)&Bsl[cur][r * 64 + (((ks * 4 + quad) ^ (r & 7)) * 8)];
            }
            #pragma unroll
            for (int mt = 0; mt < 4; mt++)
                #pragma unroll
                for (int nt = 0; nt < 2; nt++)
                    acc[mt][nt] = __builtin_amdgcn_mfma_f32_16x16x32_bf16(af[mt], bf[nt], acc[mt][nt], 0, 0, 0);
        }
    }
    #pragma unroll
    for (int mt = 0; mt < 4; mt++) {
        #pragma unroll
        for (int reg = 0; reg < 4; reg++) {
            int row = bm + mt * 16 + quad * 4 + reg;
            #pragma unroll
            for (int nt = 0; nt < 2; nt++) {
                int col = bn + w * 32 + nt * 16 + l16;
                if (col < N) {
                    if constexpr (BF16OUT)
                        ((__hip_bfloat16*)Cv)[(size_t)row * N + col] = __float2bfloat16(acc[mt][nt][reg]);
                    else
                        ((float*)Cv)[(size_t)row * N + col] = acc[mt][nt][reg];
                }
            }
        }
    }
}

// ---------------- RoPE + rank contraction, 4 tokens/block ----------
// Reads bf16 abqkv (packed 2xbf16 = 4B/lane loads), stages fp32 in LDS.
__global__ __launch_bounds__(256) void qkv_kernel(
    const __hip_bfloat16* __restrict__ ab,
    __hip_bfloat16* __restrict__ q, __hip_bfloat16* __restrict__ k,
    __hip_bfloat16* __restrict__ vT)
{
    const int tok0 = blockIdx.x * 4;
    const int w = threadIdx.x >> 6;
    const int d = threadIdx.x & 63;
    const int token = tok0 + w;
    const int b = token / TT;
    const int t = token % TT;
    __shared__ float sab[4][NQK];
    __shared__ __align__(8) __hip_bfloat16 vbuf[NHEADS][DHEAD][4];
    const __hip_bfloat16* aq = ab + (size_t)token * NQK;
    #pragma unroll
    for (int i2 = d; i2 < NQK / 2; i2 += 64) {
        unsigned int u = *(const unsigned int*)&aq[i2 * 2];
        sab[w][i2 * 2 + 0] = bfu2f((unsigned short)(u & 0xffff));
        sab[w][i2 * 2 + 1] = bfu2f((unsigned short)(u >> 16));
    }
    const float* sq  = sab[w];
    const float* skv = sab[w] + 480;
    const int i32 = d & 31;
    // 10000^(-i/32) = 2^(-i/32 * log2(10000))
    float inv_freq = exp2_hw(-(float)i32 * (13.287712379549449f / 32.0f));
    float fr = (float)t * inv_freq;
    float c = cosf(fr), s = sinf(fr);
    __syncthreads();
    float rot[4];
    #pragma unroll
    for (int r = 0; r < 4; r++) {
        float x1 = skv[r * CHDIM + NHEADS + i32];
        float x2 = skv[r * CHDIM + NHEADS + 32 + i32];
        rot[r] = (d < 32) ? (x1 * c + x2 * s) : (-x1 * s + x2 * c);
    }
    float bqv[RQn];
    #pragma unroll
    for (int r = 0; r < RQn; r++) bqv[r] = sq[r * CHDIM + NHEADS + d];
    #pragma unroll
    for (int h = 0; h < NHEADS; h++) {
        float accq = 0.0f;
        #pragma unroll
        for (int r = 0; r < RQn; r++)
            accq += sq[r * CHDIM + h] * bqv[r];
        // q-scale: 1/sqrt(64)/RQ with log2(e) folded in (flash uses 2^x).
        q[((size_t)(b * NHEADS + h) * TT + t) * DHEAD + d] =
            __float2bfloat16(accq * (0.125f / 6.0f) * 1.4426950408889634f);
        float acck = 0.0f, accv = 0.0f;
        #pragma unroll
        for (int r = 0; r < RKn; r++)
            acck += skv[r * CHDIM + h] * rot[r];
        #pragma unroll
        for (int r = 0; r < RVn; r++)
            accv += skv[(RKn + r) * CHDIM + h] * rot[RKn + r];
        k[((size_t)(b * NHEADS + h) * TT + t) * DHEAD + d] = __float2bfloat16(acck * 0.5f);
        vbuf[h][d][w] = __float2bfloat16(accv * 0.5f);
    }
    __syncthreads();
    const int t0 = tok0 % TT;
    const int b0 = tok0 / TT;
    for (int row = threadIdx.x; row < NHEADS * DHEAD; row += 256) {
        int h = row >> 6, dd = row & 63;
        *(uint2*)&vT[((size_t)(b0 * NHEADS + h) * DHEAD + dd) * TT + t0] =
            *(const uint2*)&vbuf[h][dd][0];
    }
}

// -------- P^T B-frag construction from exp'd S registers (shared helper) ----
// __builtin_amdgcn_permlane32_swap(A,B,fi,bc) -> {A',B'} where
//   A' = {A.lo lanes 0-31, B.lo delivered to lanes 32-63}
//   B' = {A.hi delivered to lanes 0-31, B.hi lanes 32-63}
static __device__ __forceinline__ void build_pfrag(
    const float* s0, const float* s1, frag16 Pf[4])
{
    #pragma unroll
    for (int k2 = 0; k2 < 4; k2++) {
        const float* sF = (k2 >= 2) ? s1 : s0;
        const int bs = 8 * (k2 & 1);
        unsigned int a0 = pk2(sF[bs + 0], sF[bs + 1]);
        unsigned int b0 = pk2(sF[bs + 2], sF[bs + 3]);
        unsigned int a1 = pk2(sF[bs + 4], sF[bs + 5]);
        unsigned int b1 = pk2(sF[bs + 6], sF[bs + 7]);
        uint2v ra = __builtin_amdgcn_permlane32_swap(a0, a1, false, false);
        uint2v rb = __builtin_amdgcn_permlane32_swap(b0, b1, false, false);
        union { frag16 f; unsigned int u[4]; } pf;
        pf.u[0] = ra[0]; pf.u[1] = rb[0]; pf.u[2] = ra[1]; pf.u[3] = rb[1];
        Pf[k2] = pf.f;
    }
}

// ---------------- single attention tile (LDS operands, XOR-swizzled) --------
static __device__ __forceinline__ void attn_tile(
    const __hip_bfloat16* __restrict__ Kc, const __hip_bfloat16* __restrict__ Vc,
    const frag16 qB[4], f32x16& O0, f32x16& O1, float& lpart,
    const int l31, const int hi, const int xi,
    const bool domask, const int kb0, const int qlane)
{
    f32x16 ST0 = {}, ST1 = {};
    __builtin_amdgcn_s_setprio(1);
    #pragma unroll
    for (int kt4 = 0; kt4 < 4; kt4++) {
        int c8 = kt4 * 2 + hi;
        frag16 kf0 = *(const frag16*)&Kc[l31 * 64 + ((c8 ^ xi) * 8)];
        frag16 kf1 = *(const frag16*)&Kc[(32 + l31) * 64 + ((c8 ^ xi) * 8)];
        ST0 = __builtin_amdgcn_mfma_f32_32x32x16_bf16(kf0, qB[kt4], ST0, 0, 0, 0);
        ST1 = __builtin_amdgcn_mfma_f32_32x32x16_bf16(kf1, qB[kt4], ST1, 0, 0, 0);
    }
    __builtin_amdgcn_s_setprio(0);
    float* s0 = (float*)&ST0;
    float* s1 = (float*)&ST1;
    if (domask) {
        int kbq = kb0 + 4 * hi;
        #pragma unroll
        for (int reg = 0; reg < 16; reg++) {
            int rowc = (reg & 3) + 8 * (reg >> 2);
            if (kbq + rowc > qlane)      s0[reg] = -1e30f;
            if (kbq + 32 + rowc > qlane) s1[reg] = -1e30f;
        }
    }
    #pragma unroll
    for (int reg = 0; reg < 16; reg++) {
        float p0 = exp2_hw(s0[reg]);
        float p1 = exp2_hw(s1[reg]);
        s0[reg] = p0; s1[reg] = p1;
        lpart += p0 + p1;
    }
    frag16 Pf[4];
    build_pfrag(s0, s1, Pf);
    __builtin_amdgcn_s_setprio(1);
    #pragma unroll
    for (int k2 = 0; k2 < 4; k2++) {
        int c8 = k2 * 2 + hi;
        frag16 vf0 = *(const frag16*)&Vc[l31 * 64 + ((c8 ^ xi) * 8)];
        frag16 vf1 = *(const frag16*)&Vc[(32 + l31) * 64 + ((c8 ^ xi) * 8)];
        O0 = __builtin_amdgcn_mfma_f32_32x32x16_bf16(vf0, Pf[k2], O0, 0, 0, 0);
        O1 = __builtin_amdgcn_mfma_f32_32x32x16_bf16(vf1, Pf[k2], O1, 0, 0, 0);
    }
    __builtin_amdgcn_s_setprio(0);
}

// ------- fused split-K causal flash attention, 512-thread blocks ------------
// R9 structure (8 waves: waves 0-3 = K-half 0, waves 4-7 = K-half 1; per-half
// dbuf staging; in-block combine; no partials/combine kernel) with the T4
// counted-vmcnt loop: STAGE(next) -> s_waitcnt vmcnt(4) (tile-kt loads are
// this wave's oldest 4; next-tile's 4 stay in flight ACROSS the barrier) ->
// bare s_barrier -> compute -> bare s_barrier (frees buf^1 for next stage).
// No vmcnt(0) drains in the loop (the __syncthreads drain was R9's residual).
// Race check: buf^1 is overwritten at iter kt only after barrier-2 of iter
// kt-1, which ends all reads of buf^1 (compute kt-1). vmcnt(0) after qB loads
// makes the FIFO count exact (qB retires before staging arithmetic).
// XCD pinning (T1): Bid&7 = XCD, 4 bh/XCD -> 2MB K/V set in 4MB L2.
__global__ __launch_bounds__(512, 4) void flash_mfma(
    const __hip_bfloat16* __restrict__ q, const __hip_bfloat16* __restrict__ k,
    const __hip_bfloat16* __restrict__ vT, __hip_bfloat16* __restrict__ y)
{
    const int Bid = blockIdx.x;          // 512
    const int m = Bid & 255;
    const int half = Bid >> 8;
    const int xcd = m & 7;
    const int bh  = xcd * 4 + ((m >> 3) & 3);
    const int qx  = m >> 5;              // 0..7
    const int qt  = half ? qx : (15 - qx);
    const int nst = qt + 1;

    const int tid = threadIdx.x;
    const int w8 = tid >> 6;             // 0..7
    const int part = w8 >> 2;
    const int w = w8 & 3;
    const int lane = tid & 63;
    const int l31 = lane & 31;
    const int hi = lane >> 5;
    const int xi = l31 & 7;
    const int paddr = (lane ^ 32) << 2;
    const int k0 = part * nst;

    __shared__ __align__(16) char smem[65536];
    __hip_bfloat16* Ks = (__hip_bfloat16*)(smem + part * 32768);           // [2][4096]
    __hip_bfloat16* Vs = (__hip_bfloat16*)(smem + part * 32768 + 16384);   // [2][4096]

    const size_t base = (size_t)bh * TT * DHEAD;
    const __hip_bfloat16* qb = q + base;
    const __hip_bfloat16* kb = k + base;
    const __hip_bfloat16* vb = vT + base;

    const int ktd = 2 * qt + (w >> 1);           // this wave's diagonal tile
    const int qlane = qt * 128 + w * 32 + l31;   // this lane's q row

    int offK[2], offV[2];
    #pragma unroll
    for (int j = 0; j < 2; j++) {
        int Lc = w * 128 + j * 64 + lane;
        int r = Lc >> 3, c8 = Lc & 7, g8 = c8 ^ (r & 7);
        offK[j] = r * 64 + g8 * 8;
        offV[j] = r * TT + g8 * 8;
    }

    frag16 qB[4];
    #pragma unroll
    for (int kt4 = 0; kt4 < 4; kt4++)
        qB[kt4] = *(const frag16*)&qb[(size_t)qlane * DHEAD + kt4 * 16 + hi * 8];
    // retire qB loads so the staging vmcnt arithmetic below is exact
    asm volatile("s_waitcnt vmcnt(0)" ::: "memory");

#define STAGE_TILE(PHYS, BUF)                                                          \
    _Pragma("unroll")                                                                  \
    for (int j = 0; j < 2; j++) {                                                      \
        __builtin_amdgcn_global_load_lds(AS1(kb + (size_t)(PHYS) * 4096 + offK[j]),    \
                                         AS3(&Ks[(BUF) * 4096 + w * 1024 + j * 512]), 16, 0, 0); \
        __builtin_amdgcn_global_load_lds(AS1(vb + (size_t)(PHYS) * 64 + offV[j]),      \
                                         AS3(&Vs[(BUF) * 4096 + w * 1024 + j * 512]), 16, 0, 0); \
    }

    f32x16 O0 = {}, O1 = {};
    float l = 0.0f;

    STAGE_TILE(k0, 0);
    for (int kt = 0; kt < nst; kt++) {
        const int cur = kt & 1;
        if (kt + 1 < nst) {
            STAGE_TILE(k0 + kt + 1, cur ^ 1);
            // outstanding = 8; wait to <=4 -> tile kt's 4 (oldest) landed,
            // tile kt+1's 4 remain in flight across the barrier (T4).
            asm volatile("s_waitcnt vmcnt(4)" ::: "memory");
        } else {
            asm volatile("s_waitcnt vmcnt(0)" ::: "memory");
        }
        __builtin_amdgcn_s_barrier();          // all waves' tile-kt loads done
        __builtin_amdgcn_sched_barrier(0);     // rule #18: pin LDS reads after
        const int phys = k0 + kt;
        if (phys <= ktd)
            attn_tile(Ks + cur * 4096, Vs + cur * 4096, qB, O0, O1, l,
                      l31, hi, xi, phys == ktd, phys * 64, qlane);
        __builtin_amdgcn_s_barrier();          // frees buf cur^1 for next stage
    }
#undef STAGE_TILE

    // ---- in-block combine: part1 -> LDS (over dead staging), part0 adds ----
    __syncthreads();                       // full drain once; staging regions dead
    float* Oex = (float*)smem;             // 4 pairs x 64 lanes x 33 floats
    float* lex = (float*)(smem + 33792);   // 4 x 64 floats
    float* o0 = (float*)&O0;
    float* o1 = (float*)&O1;
    if (part == 1) {
        float* dst = Oex + (w * 64 + lane) * 33;
        #pragma unroll
        for (int i = 0; i < 16; i++) { dst[i] = o0[i]; dst[16 + i] = o1[i]; }
        lex[w * 64 + lane] = l;
    }
    __syncthreads();
    if (part == 0) {
        const float* src = Oex + (w * 64 + lane) * 33;
        #pragma unroll
        for (int i = 0; i < 16; i++) { o0[i] += src[i]; o1[i] += src[16 + i]; }
        l += lex[w * 64 + lane];
        float lother = __int_as_float(__builtin_amdgcn_ds_bpermute(paddr, __float_as_int(l)));
        float inv = 1.0f / (l + lother);
        const int b = bh >> 4, h = bh & 15;
        __hip_bfloat16* yp = y + ((size_t)(b * TT + qlane)) * DDim + h * DHEAD;
        #pragma unroll
        for (int gg = 0; gg < 4; gg++) {
            int d0 = 8 * gg + 4 * hi;
            uint2 pa, pb;
            pa.x = pk2(o0[4*gg+0] * inv, o0[4*gg+1] * inv);
            pa.y = pk2(o0[4*gg+2] * inv, o0[4*gg+3] * inv);
            pb.x = pk2(o1[4*gg+0] * inv, o1[4*gg+1] * inv);
            pb.y = pk2(o1[4*gg+2] * inv, o1[4*gg+3] * inv);
            *(uint2*)&yp[d0] = pa;
            *(uint2*)&yp[32 + d0] = pb;
        }
    }
}

extern "C" void kernel_launch(void* const* d_in, const int* in_sizes, int n_in,
                              void* d_out, int out_size, void* d_ws, size_t ws_size,
                              hipStream_t stream) {
    const float* x      = (const float*)d_in[0];
    const float* W_abq  = (const float*)d_in[1];
    const float* W_abkv = (const float*)d_in[2];
    const float* W_o    = (const float*)d_in[3];
    float* out = (float*)d_out;

    char* ws = (char*)d_ws;
    __hip_bfloat16* xb   = (__hip_bfloat16*)ws;  ws += (size_t)4194304 * 2;
    __hip_bfloat16* wqk  = (__hip_bfloat16*)ws;  ws += (size_t)NQK * 1024 * 2;
    __hip_bfloat16* wo_b = (__hip_bfloat16*)ws;  ws += (size_t)1048576 * 2;
    __hip_bfloat16* abqkv = (__hip_bfloat16*)ws; ws += (size_t)4096 * NQK * 2;
    __hip_bfloat16* qb = (__hip_bfloat16*)ws;    ws += (size_t)4194304 * 2;
    __hip_bfloat16* kb = (__hip_bfloat16*)ws;    ws += (size_t)4194304 * 2;
    __hip_bfloat16* vT = (__hip_bfloat16*)ws;    ws += (size_t)4194304 * 2;
    __hip_bfloat16* yb = (__hip_bfloat16*)ws;    ws += (size_t)4194304 * 2;

    cvt_all<<<dim3(5920), dim3(256), 0, stream>>>(x, W_abq, W_abkv, W_o, xb, wqk, wo_b);
    gemm_bf16<true><<<dim3(7, 64), dim3(256), 0, stream>>>(xb, wqk, abqkv, 4096, NQK, 1024);
    qkv_kernel<<<dim3(1024), dim3(256), 0, stream>>>(abqkv, qb, kb, vT);
    flash_mfma<<<dim3(512), dim3(512), 0, stream>>>(qb, kb, vT, yb);
    gemm_bf16<false><<<dim3(8, 64), dim3(256), 0, stream>>>(yb, wo_b, out, 4096, 1024, 1024);
}

// Round 12
// 160.464 us; speedup vs baseline: 1.1372x; 1.0021x over previous
//
#include <hip/hip_runtime.h>
#include <hip/hip_bf16.h>
#include <math.h>

#define NHEADS 16
#define DHEAD  64
#define CHDIM  80
#define RQn    6
#define RKn    2
#define RVn    2
#define BB     2
#define TT     2048
#define DDim   1024
#define NQK    800   // 480 + 320 combined projection rows

using frag16 = __attribute__((ext_vector_type(8))) short;   // 8 bf16 (4 VGPR)
using f32x4  = __attribute__((ext_vector_type(4))) float;   // 4 fp32 acc
using f32x16 = __attribute__((ext_vector_type(16))) float;  // 32x32 acc
using uint2v = __attribute__((ext_vector_type(2))) unsigned int;

#define AS1(p) ((const __attribute__((address_space(1))) unsigned int*)(p))
#define AS3(p) ((__attribute__((address_space(3))) unsigned int*)(p))

static __device__ __forceinline__ unsigned short bf16_bits(float f) {
    __hip_bfloat16 h = __float2bfloat16(f);
    return *(unsigned short*)&h;
}
static __device__ __forceinline__ unsigned int pk2(float a, float b) {
    return ((unsigned int)bf16_bits(b) << 16) | (unsigned int)bf16_bits(a);
}
static __device__ __forceinline__ float bfu2f(unsigned short u) {
    return __uint_as_float(((unsigned int)u) << 16);
}
// HW exp2 via the proper intrinsic (hazard-safe). log2(e) folded into q-scale.
static __device__ __forceinline__ float exp2_hw(float x) {
    return __builtin_amdgcn_exp2f(x);
}

// ---------------- fused fp32 -> bf16 convert (4 segments, 1 launch) ----------
__global__ __launch_bounds__(256) void cvt_all(
    const float* __restrict__ x, const float* __restrict__ wq,
    const float* __restrict__ wk, const float* __restrict__ wo,
    __hip_bfloat16* __restrict__ xb, __hip_bfloat16* __restrict__ wqk,
    __hip_bfloat16* __restrict__ wob)
{
    int bid = blockIdx.x;
    const float* src; __hip_bfloat16* dst; int n4;
    if (bid < 4096)      { src = x;  dst = xb;            n4 = 1048576; }
    else if (bid < 4576) { bid -= 4096; src = wq; dst = wqk;           n4 = 122880; }
    else if (bid < 4896) { bid -= 4576; src = wk; dst = wqk + 491520;  n4 = 81920; }
    else                 { bid -= 4896; src = wo; dst = wob;           n4 = 262144; }
    int i = bid * 256 + threadIdx.x;
    if (i < n4) {
        float4 v = *(const float4*)&src[i * 4];
        ushort4 o;
        o.x = bf16_bits(v.x); o.y = bf16_bits(v.y);
        o.z = bf16_bits(v.z); o.w = bf16_bits(v.w);
        *(ushort4*)&dst[i * 4] = o;
    }
}

// ---------- GEMM: C[M,N] = A[M,K]_bf16 * W[N,K]_bf16^T, 64x128 tile ---------
// BF16OUT: write bf16 C (used for abqkv to halve the round-trip traffic).
template <bool BF16OUT>
__global__ __launch_bounds__(256) void gemm_bf16(
    const __hip_bfloat16* __restrict__ A, const __hip_bfloat16* __restrict__ W,
    void* __restrict__ Cv, int M, int N, int K)
{
    __shared__ __hip_bfloat16 Asl[2][64 * 64];
    __shared__ __hip_bfloat16 Bsl[2][128 * 64];
    const int tid = threadIdx.x;
    const int w = tid >> 6, lane = tid & 63;
    const int l16 = lane & 15, quad = lane >> 4;
    const int bm = blockIdx.y * 64, bn = blockIdx.x * 128;

    // staging geometry
    int rSA[2], cSA[2];
    #pragma unroll
    for (int j = 0; j < 2; j++) {
        int L = (w * 2 + j) * 64 + lane;
        rSA[j] = L >> 3;
        cSA[j] = (L & 7) ^ (rSA[j] & 7);
    }
    int rSB[4], cSB[4];
    #pragma unroll
    for (int j = 0; j < 4; j++) {
        int L = (w * 4 + j) * 64 + lane;
        int r = L >> 3;
        cSB[j] = (L & 7) ^ (r & 7);
        int rb = bn + r;
        rSB[j] = (rb < N) ? rb : (N - 1);
    }

    f32x4 acc[4][2];
    #pragma unroll
    for (int mt = 0; mt < 4; mt++)
        #pragma unroll
        for (int nt = 0; nt < 2; nt++)
            acc[mt][nt] = (f32x4){0.f, 0.f, 0.f, 0.f};

    const int nK = K >> 6;
    #pragma unroll
    for (int j = 0; j < 2; j++)
        __builtin_amdgcn_global_load_lds(AS1(A + (size_t)(bm + rSA[j]) * K + cSA[j] * 8),
                                         AS3(&Asl[0][(w * 2 + j) * 512]), 16, 0, 0);
    #pragma unroll
    for (int j = 0; j < 4; j++)
        __builtin_amdgcn_global_load_lds(AS1(W + (size_t)rSB[j] * K + cSB[j] * 8),
                                         AS3(&Bsl[0][(w * 4 + j) * 512]), 16, 0, 0);

    for (int kk = 0; kk < nK; kk++) {
        const int cur = kk & 1;
        __syncthreads();
        if (kk + 1 < nK) {
            const int k1 = (kk + 1) * 64;
            #pragma unroll
            for (int j = 0; j < 2; j++)
                __builtin_amdgcn_global_load_lds(AS1(A + (size_t)(bm + rSA[j]) * K + k1 + cSA[j] * 8),
                                                 AS3(&Asl[cur ^ 1][(w * 2 + j) * 512]), 16, 0, 0);
            #pragma unroll
            for (int j = 0; j < 4; j++)
                __builtin_amdgcn_global_load_lds(AS1(W + (size_t)rSB[j] * K + k1 + cSB[j] * 8),
                                                 AS3(&Bsl[cur ^ 1][(w * 4 + j) * 512]), 16, 0, 0);
        }
        #pragma unroll
        for (int ks = 0; ks < 2; ks++) {
            frag16 af[4], bf[2];
            #pragma unroll
            for (int mt = 0; mt < 4; mt++) {
                int r = mt * 16 + l16;
                af[mt] = *(const frag16*)&Asl[cur][r * 64 + (((ks * 4 + quad) ^ (r & 7)) * 8)];
            }
            #pragma unroll
            for (int nt = 0; nt < 2; nt++) {
                int r = w * 32 + nt * 16 + l16;
                bf[nt] = *(const frag16*)&Bsl[cur][r * 64 + (((ks * 4 + quad) ^ (r & 7)) * 8)];
            }
            #pragma unroll
            for (int mt = 0; mt < 4; mt++)
                #pragma unroll
                for (int nt = 0; nt < 2; nt++)
                    acc[mt][nt] = __builtin_amdgcn_mfma_f32_16x16x32_bf16(af[mt], bf[nt], acc[mt][nt], 0, 0, 0);
        }
    }
    #pragma unroll
    for (int mt = 0; mt < 4; mt++) {
        #pragma unroll
        for (int reg = 0; reg < 4; reg++) {
            int row = bm + mt * 16 + quad * 4 + reg;
            #pragma unroll
            for (int nt = 0; nt < 2; nt++) {
                int col = bn + w * 32 + nt * 16 + l16;
                if (col < N) {
                    if constexpr (BF16OUT)
                        ((__hip_bfloat16*)Cv)[(size_t)row * N + col] = __float2bfloat16(acc[mt][nt][reg]);
                    else
                        ((float*)Cv)[(size_t)row * N + col] = acc[mt][nt][reg];
                }
            }
        }
    }
}

// ---------------- RoPE + rank contraction, 4 tokens/block ----------
// Reads bf16 abqkv (packed 2xbf16 = 4B/lane loads), stages fp32 in LDS.
__global__ __launch_bounds__(256) void qkv_kernel(
    const __hip_bfloat16* __restrict__ ab,
    __hip_bfloat16* __restrict__ q, __hip_bfloat16* __restrict__ k,
    __hip_bfloat16* __restrict__ vT)
{
    const int tok0 = blockIdx.x * 4;
    const int w = threadIdx.x >> 6;
    const int d = threadIdx.x & 63;
    const int token = tok0 + w;
    const int b = token / TT;
    const int t = token % TT;
    __shared__ float sab[4][NQK];
    __shared__ __align__(8) __hip_bfloat16 vbuf[NHEADS][DHEAD][4];
    const __hip_bfloat16* aq = ab + (size_t)token * NQK;
    #pragma unroll
    for (int i2 = d; i2 < NQK / 2; i2 += 64) {
        unsigned int u = *(const unsigned int*)&aq[i2 * 2];
        sab[w][i2 * 2 + 0] = bfu2f((unsigned short)(u & 0xffff));
        sab[w][i2 * 2 + 1] = bfu2f((unsigned short)(u >> 16));
    }
    const float* sq  = sab[w];
    const float* skv = sab[w] + 480;
    const int i32 = d & 31;
    // 10000^(-i/32) = 2^(-i/32 * log2(10000))
    float inv_freq = exp2_hw(-(float)i32 * (13.287712379549449f / 32.0f));
    float fr = (float)t * inv_freq;
    float c = cosf(fr), s = sinf(fr);
    __syncthreads();
    float rot[4];
    #pragma unroll
    for (int r = 0; r < 4; r++) {
        float x1 = skv[r * CHDIM + NHEADS + i32];
        float x2 = skv[r * CHDIM + NHEADS + 32 + i32];
        rot[r] = (d < 32) ? (x1 * c + x2 * s) : (-x1 * s + x2 * c);
    }
    float bqv[RQn];
    #pragma unroll
    for (int r = 0; r < RQn; r++) bqv[r] = sq[r * CHDIM + NHEADS + d];
    #pragma unroll
    for (int h = 0; h < NHEADS; h++) {
        float accq = 0.0f;
        #pragma unroll
        for (int r = 0; r < RQn; r++)
            accq += sq[r * CHDIM + h] * bqv[r];
        // q-scale: 1/sqrt(64)/RQ with log2(e) folded in (flash uses 2^x).
        q[((size_t)(b * NHEADS + h) * TT + t) * DHEAD + d] =
            __float2bfloat16(accq * (0.125f / 6.0f) * 1.4426950408889634f);
        float acck = 0.0f, accv = 0.0f;
        #pragma unroll
        for (int r = 0; r < RKn; r++)
            acck += skv[r * CHDIM + h] * rot[r];
        #pragma unroll
        for (int r = 0; r < RVn; r++)
            accv += skv[(RKn + r) * CHDIM + h] * rot[RKn + r];
        k[((size_t)(b * NHEADS + h) * TT + t) * DHEAD + d] = __float2bfloat16(acck * 0.5f);
        vbuf[h][d][w] = __float2bfloat16(accv * 0.5f);
    }
    __syncthreads();
    const int t0 = tok0 % TT;
    const int b0 = tok0 / TT;
    for (int row = threadIdx.x; row < NHEADS * DHEAD; row += 256) {
        int h = row >> 6, dd = row & 63;
        *(uint2*)&vT[((size_t)(b0 * NHEADS + h) * DHEAD + dd) * TT + t0] =
            *(const uint2*)&vbuf[h][dd][0];
    }
}

// -------- P^T B-frag construction from exp'd S registers (shared helper) ----
// __builtin_amdgcn_permlane32_swap(A,B,fi,bc) -> {A',B'} where
//   A' = {A.lo lanes 0-31, B.lo delivered to lanes 32-63}
//   B' = {A.hi delivered to lanes 0-31, B.hi lanes 32-63}
static __device__ __forceinline__ void build_pfrag(
    const float* s0, const float* s1, frag16 Pf[4])
{
    #pragma unroll
    for (int k2 = 0; k2 < 4; k2++) {
        const float* sF = (k2 >= 2) ? s1 : s0;
        const int bs = 8 * (k2 & 1);
        unsigned int a0 = pk2(sF[bs + 0], sF[bs + 1]);
        unsigned int b0 = pk2(sF[bs + 2], sF[bs + 3]);
        unsigned int a1 = pk2(sF[bs + 4], sF[bs + 5]);
        unsigned int b1 = pk2(sF[bs + 6], sF[bs + 7]);
        uint2v ra = __builtin_amdgcn_permlane32_swap(a0, a1, false, false);
        uint2v rb = __builtin_amdgcn_permlane32_swap(b0, b1, false, false);
        union { frag16 f; unsigned int u[4]; } pf;
        pf.u[0] = ra[0]; pf.u[1] = rb[0]; pf.u[2] = ra[1]; pf.u[3] = rb[1];
        Pf[k2] = pf.f;
    }
}

// ---------------- single attention tile (LDS operands, XOR-swizzled) --------
static __device__ __forceinline__ void attn_tile(
    const __hip_bfloat16* __restrict__ Kc, const __hip_bfloat16* __restrict__ Vc,
    const frag16 qB[4], f32x16& O0, f32x16& O1, float& lpart,
    const int l31, const int hi, const int xi,
    const bool domask, const int kb0, const int qlane)
{
    f32x16 ST0 = {}, ST1 = {};
    __builtin_amdgcn_s_setprio(1);
    #pragma unroll
    for (int kt4 = 0; kt4 < 4; kt4++) {
        int c8 = kt4 * 2 + hi;
        frag16 kf0 = *(const frag16*)&Kc[l31 * 64 + ((c8 ^ xi) * 8)];
        frag16 kf1 = *(const frag16*)&Kc[(32 + l31) * 64 + ((c8 ^ xi) * 8)];
        ST0 = __builtin_amdgcn_mfma_f32_32x32x16_bf16(kf0, qB[kt4], ST0, 0, 0, 0);
        ST1 = __builtin_amdgcn_mfma_f32_32x32x16_bf16(kf1, qB[kt4], ST1, 0, 0, 0);
    }
    __builtin_amdgcn_s_setprio(0);
    float* s0 = (float*)&ST0;
    float* s1 = (float*)&ST1;
    if (domask) {
        int kbq = kb0 + 4 * hi;
        #pragma unroll
        for (int reg = 0; reg < 16; reg++) {
            int rowc = (reg & 3) + 8 * (reg >> 2);
            if (kbq + rowc > qlane)      s0[reg] = -1e30f;
            if (kbq + 32 + rowc > qlane) s1[reg] = -1e30f;
        }
    }
    #pragma unroll
    for (int reg = 0; reg < 16; reg++) {
        float p0 = exp2_hw(s0[reg]);
        float p1 = exp2_hw(s1[reg]);
        s0[reg] = p0; s1[reg] = p1;
        lpart += p0 + p1;
    }
    frag16 Pf[4];
    build_pfrag(s0, s1, Pf);
    __builtin_amdgcn_s_setprio(1);
    #pragma unroll
    for (int k2 = 0; k2 < 4; k2++) {
        int c8 = k2 * 2 + hi;
        frag16 vf0 = *(const frag16*)&Vc[l31 * 64 + ((c8 ^ xi) * 8)];
        frag16 vf1 = *(const frag16*)&Vc[(32 + l31) * 64 + ((c8 ^ xi) * 8)];
        O0 = __builtin_amdgcn_mfma_f32_32x32x16_bf16(vf0, Pf[k2], O0, 0, 0, 0);
        O1 = __builtin_amdgcn_mfma_f32_32x32x16_bf16(vf1, Pf[k2], O1, 0, 0, 0);
    }
    __builtin_amdgcn_s_setprio(0);
}

// ---- one full R9-style phase: q-tile qt, split-K halves, in-block combine --
static __device__ __forceinline__ void flash_phase(
    const int qt, const int part, const int w, const int lane,
    const int l31, const int hi, const int xi, const int paddr,
    const __hip_bfloat16* __restrict__ qb, const __hip_bfloat16* __restrict__ kb,
    const __hip_bfloat16* __restrict__ vb, __hip_bfloat16* __restrict__ y,
    const int bh, char* smem)
{
    const int nst = qt + 1;
    const int k0 = part * nst;
    __hip_bfloat16* Ks = (__hip_bfloat16*)(smem + part * 32768);           // [2][4096]
    __hip_bfloat16* Vs = (__hip_bfloat16*)(smem + part * 32768 + 16384);   // [2][4096]

    const int ktd = 2 * qt + (w >> 1);           // this wave's diagonal tile
    const int qlane = qt * 128 + w * 32 + l31;   // this lane's q row

    int offK[2], offV[2];
    #pragma unroll
    for (int j = 0; j < 2; j++) {
        int Lc = w * 128 + j * 64 + lane;
        int r = Lc >> 3, c8 = Lc & 7, g8 = c8 ^ (r & 7);
        offK[j] = r * 64 + g8 * 8;
        offV[j] = r * TT + g8 * 8;
    }

    frag16 qB[4];
    #pragma unroll
    for (int kt4 = 0; kt4 < 4; kt4++)
        qB[kt4] = *(const frag16*)&qb[(size_t)qlane * DHEAD + kt4 * 16 + hi * 8];

    f32x16 O0 = {}, O1 = {};
    float l = 0.0f;

    #pragma unroll
    for (int j = 0; j < 2; j++) {
        __builtin_amdgcn_global_load_lds(AS1(kb + (size_t)k0 * 4096 + offK[j]),
                                         AS3(&Ks[w * 1024 + j * 512]), 16, 0, 0);
        __builtin_amdgcn_global_load_lds(AS1(vb + (size_t)k0 * 64 + offV[j]),
                                         AS3(&Vs[w * 1024 + j * 512]), 16, 0, 0);
    }

    for (int kt = 0; kt < nst; kt++) {
        const int cur = kt & 1;
        __syncthreads();
        if (kt + 1 < nst) {
            const int phys1 = k0 + kt + 1;
            #pragma unroll
            for (int j = 0; j < 2; j++) {
                __builtin_amdgcn_global_load_lds(AS1(kb + (size_t)phys1 * 4096 + offK[j]),
                                                 AS3(&Ks[(cur ^ 1) * 4096 + w * 1024 + j * 512]), 16, 0, 0);
                __builtin_amdgcn_global_load_lds(AS1(vb + (size_t)phys1 * 64 + offV[j]),
                                                 AS3(&Vs[(cur ^ 1) * 4096 + w * 1024 + j * 512]), 16, 0, 0);
            }
        }
        const int phys = k0 + kt;
        if (phys <= ktd)
            attn_tile(Ks + cur * 4096, Vs + cur * 4096, qB, O0, O1, l,
                      l31, hi, xi, phys == ktd, phys * 64, qlane);
    }

    // ---- in-block combine: part1 -> LDS (over dead staging), part0 adds ----
    __syncthreads();                       // all staging reads complete
    float* Oex = (float*)smem;             // 4 pairs x 64 lanes x 33 floats
    float* lex = (float*)(smem + 33792);   // 4 x 64 floats
    float* o0 = (float*)&O0;
    float* o1 = (float*)&O1;
    if (part == 1) {
        float* dst = Oex + (w * 64 + lane) * 33;
        #pragma unroll
        for (int i = 0; i < 16; i++) { dst[i] = o0[i]; dst[16 + i] = o1[i]; }
        lex[w * 64 + lane] = l;
    }
    __syncthreads();
    if (part == 0) {
        const float* src = Oex + (w * 64 + lane) * 33;
        #pragma unroll
        for (int i = 0; i < 16; i++) { o0[i] += src[i]; o1[i] += src[16 + i]; }
        l += lex[w * 64 + lane];
        float lother = __int_as_float(__builtin_amdgcn_ds_bpermute(paddr, __float_as_int(l)));
        float inv = 1.0f / (l + lother);
        const int b = bh >> 4, h = bh & 15;
        __hip_bfloat16* yp = y + ((size_t)(b * TT + qlane)) * DDim + h * DHEAD;
        #pragma unroll
        for (int gg = 0; gg < 4; gg++) {
            int d0 = 8 * gg + 4 * hi;
            uint2 pa, pb;
            pa.x = pk2(o0[4*gg+0] * inv, o0[4*gg+1] * inv);
            pa.y = pk2(o0[4*gg+2] * inv, o0[4*gg+3] * inv);
            pb.x = pk2(o1[4*gg+0] * inv, o1[4*gg+1] * inv);
            pb.y = pk2(o1[4*gg+2] * inv, o1[4*gg+3] * inv);
            *(uint2*)&yp[d0] = pa;
            *(uint2*)&yp[32 + d0] = pb;
        }
    }
}

// ------- fused split-K causal flash, 256 EQUAL-LENGTH 512-thread blocks -----
// Block (bh, s) runs TWO R9-phases sequentially: q-tile 15-s (16-s steps)
// then q-tile s (s+1 steps) = exactly 17 staging steps for EVERY block.
// Grid 256 = one block per CU: perfect CU-level balance regardless of
// dispatch order (G16-safe) - fixes the makespan risk of R9's 2-block/CU
// same-qt pairing (heaviest CU did ~2x mean). Inner structure per phase is
// identical R9: 8 waves (waves 0-3 K-half 0, 4-7 K-half 1), per-half dbuf
// staging, in-block combine over dead staging LDS, direct bf16 y-write.
// XCD pinning (T1): Bid&7 = XCD, 4 bh/XCD -> 2MB K/V set in 4MB L2.
__global__ __launch_bounds__(512, 4) void flash_mfma(
    const __hip_bfloat16* __restrict__ q, const __hip_bfloat16* __restrict__ k,
    const __hip_bfloat16* __restrict__ vT, __hip_bfloat16* __restrict__ y)
{
    const int Bid = blockIdx.x;          // 256
    const int xcd = Bid & 7;
    const int bh  = xcd * 4 + ((Bid >> 3) & 3);
    const int s   = Bid >> 5;            // 0..7

    const int tid = threadIdx.x;
    const int w8 = tid >> 6;             // 0..7
    const int part = w8 >> 2;
    const int w = w8 & 3;
    const int lane = tid & 63;
    const int l31 = lane & 31;
    const int hi = lane >> 5;
    const int xi = l31 & 7;
    const int paddr = (lane ^ 32) << 2;

    __shared__ __align__(16) char smem[65536];

    const size_t base = (size_t)bh * TT * DHEAD;
    const __hip_bfloat16* qb = q + base;
    const __hip_bfloat16* kb = k + base;
    const __hip_bfloat16* vb = vT + base;

    // phase 1: heavy q-tile (16-s steps)
    flash_phase(15 - s, part, w, lane, l31, hi, xi, paddr, qb, kb, vb, y, bh, smem);
    __syncthreads();   // part0's combine-reads done before phase-2 staging
    // phase 2: light q-tile (s+1 steps) -> total 17 steps per block, uniform
    flash_phase(s, part, w, lane, l31, hi, xi, paddr, qb, kb, vb, y, bh, smem);
}

extern "C" void kernel_launch(void* const* d_in, const int* in_sizes, int n_in,
                              void* d_out, int out_size, void* d_ws, size_t ws_size,
                              hipStream_t stream) {
    const float* x      = (const float*)d_in[0];
    const float* W_abq  = (const float*)d_in[1];
    const float* W_abkv = (const float*)d_in[2];
    const float* W_o    = (const float*)d_in[3];
    float* out = (float*)d_out;

    char* ws = (char*)d_ws;
    __hip_bfloat16* xb   = (__hip_bfloat16*)ws;  ws += (size_t)4194304 * 2;
    __hip_bfloat16* wqk  = (__hip_bfloat16*)ws;  ws += (size_t)NQK * 1024 * 2;
    __hip_bfloat16* wo_b = (__hip_bfloat16*)ws;  ws += (size_t)1048576 * 2;
    __hip_bfloat16* abqkv = (__hip_bfloat16*)ws; ws += (size_t)4096 * NQK * 2;
    __hip_bfloat16* qb = (__hip_bfloat16*)ws;    ws += (size_t)4194304 * 2;
    __hip_bfloat16* kb = (__hip_bfloat16*)ws;    ws += (size_t)4194304 * 2;
    __hip_bfloat16* vT = (__hip_bfloat16*)ws;    ws += (size_t)4194304 * 2;
    __hip_bfloat16* yb = (__hip_bfloat16*)ws;    ws += (size_t)4194304 * 2;

    cvt_all<<<dim3(5920), dim3(256), 0, stream>>>(x, W_abq, W_abkv, W_o, xb, wqk, wo_b);
    gemm_bf16<true><<<dim3(7, 64), dim3(256), 0, stream>>>(xb, wqk, abqkv, 4096, NQK, 1024);
    qkv_kernel<<<dim3(1024), dim3(256), 0, stream>>>(abqkv, qb, kb, vT);
    flash_mfma<<<dim3(256), dim3(512), 0, stream>>>(qb, kb, vT, yb);
    gemm_bf16<false><<<dim3(8, 64), dim3(256), 0, stream>>>(yb, wo_b, out, 4096, 1024, 1024);
}

// Round 13
// 160.320 us; speedup vs baseline: 1.1382x; 1.0009x over previous
//
#include <hip/hip_runtime.h>
#include <hip/hip_bf16.h>
#include <math.h>

#define NHEADS 16
#define DHEAD  64
#define CHDIM  80
#define RQn    6
#define RKn    2
#define RVn    2
#define BB     2
#define TT     2048
#define DDim   1024
#define NQK    800   // 480 + 320 combined projection rows

using frag16 = __attribute__((ext_vector_type(8))) short;   // 8 bf16 (4 VGPR)
using f32x4  = __attribute__((ext_vector_type(4))) float;   // 4 fp32 acc
using f32x16 = __attribute__((ext_vector_type(16))) float;  // 32x32 acc
using uint2v = __attribute__((ext_vector_type(2))) unsigned int;

#define AS1(p) ((const __attribute__((address_space(1))) unsigned int*)(p))
#define AS3(p) ((__attribute__((address_space(3))) unsigned int*)(p))

static __device__ __forceinline__ unsigned short bf16_bits(float f) {
    __hip_bfloat16 h = __float2bfloat16(f);
    return *(unsigned short*)&h;
}
static __device__ __forceinline__ unsigned int pk2(float a, float b) {
    return ((unsigned int)bf16_bits(b) << 16) | (unsigned int)bf16_bits(a);
}
static __device__ __forceinline__ float bfu2f(unsigned short u) {
    return __uint_as_float(((unsigned int)u) << 16);
}
// HW exp2 via the proper intrinsic (hazard-safe). log2(e) folded into q-scale.
static __device__ __forceinline__ float exp2_hw(float x) {
    return __builtin_amdgcn_exp2f(x);
}

// ------------- fp32 -> bf16 convert, WEIGHTS ONLY (x is fused into gemm1) ---
__global__ __launch_bounds__(256) void cvt_w(
    const float* __restrict__ wq, const float* __restrict__ wk,
    const float* __restrict__ wo,
    __hip_bfloat16* __restrict__ wqk, __hip_bfloat16* __restrict__ wob)
{
    int bid = blockIdx.x;                 // 1824
    const float* src; __hip_bfloat16* dst; int n4;
    if (bid < 480)      { src = wq; dst = wqk;           n4 = 122880; }
    else if (bid < 800) { bid -= 480; src = wk; dst = wqk + 491520; n4 = 81920; }
    else                { bid -= 800; src = wo; dst = wob;          n4 = 262144; }
    int i = bid * 256 + threadIdx.x;
    if (i < n4) {
        float4 v = *(const float4*)&src[i * 4];
        ushort4 o;
        o.x = bf16_bits(v.x); o.y = bf16_bits(v.y);
        o.z = bf16_bits(v.z); o.w = bf16_bits(v.w);
        *(ushort4*)&dst[i * 4] = o;
    }
}

// ---------- GEMM: C[M,N] = A[M,K] * W[N,K]_bf16^T, 64x128 tile --------------
// BF16OUT: write bf16 C (used for abqkv to halve the round-trip traffic).
// AFP32: A source is fp32; reg-stage (2x float4 -> cvt -> ds_write_b128 at
// the identical swizzled LDS slot) - eliminates the x->xb round trip. The
// produced LDS bytes are bit-identical to the bf16 path (same rounding).
template <bool BF16OUT, bool AFP32>
__global__ __launch_bounds__(256) void gemm_bf16(
    const void* __restrict__ Av, const __hip_bfloat16* __restrict__ W,
    void* __restrict__ Cv, int M, int N, int K)
{
    __shared__ __hip_bfloat16 Asl[2][64 * 64];
    __shared__ __hip_bfloat16 Bsl[2][128 * 64];
    const int tid = threadIdx.x;
    const int w = tid >> 6, lane = tid & 63;
    const int l16 = lane & 15, quad = lane >> 4;
    const int bm = blockIdx.y * 64, bn = blockIdx.x * 128;
    const __hip_bfloat16* Ab = (const __hip_bfloat16*)Av;
    const float* Af = (const float*)Av;

    // staging geometry
    int rSA[2], cSA[2];
    #pragma unroll
    for (int j = 0; j < 2; j++) {
        int L = (w * 2 + j) * 64 + lane;
        rSA[j] = L >> 3;
        cSA[j] = (L & 7) ^ (rSA[j] & 7);
    }
    int rSB[4], cSB[4];
    #pragma unroll
    for (int j = 0; j < 4; j++) {
        int L = (w * 4 + j) * 64 + lane;
        int r = L >> 3;
        cSB[j] = (L & 7) ^ (r & 7);
        int rb = bn + r;
        rSB[j] = (rb < N) ? rb : (N - 1);
    }

    f32x4 acc[4][2];
    #pragma unroll
    for (int mt = 0; mt < 4; mt++)
        #pragma unroll
        for (int nt = 0; nt < 2; nt++)
            acc[mt][nt] = (f32x4){0.f, 0.f, 0.f, 0.f};

    const int nK = K >> 6;

#define STAGE_A(K1, BUF)                                                               \
    _Pragma("unroll")                                                                  \
    for (int j = 0; j < 2; j++) {                                                      \
        if constexpr (AFP32) {                                                         \
            const float* ap = Af + (size_t)(bm + rSA[j]) * K + (K1) + cSA[j] * 8;      \
            float4 v0 = *(const float4*)ap;                                            \
            float4 v1 = *(const float4*)(ap + 4);                                      \
            union { frag16 f; unsigned int u[4]; } pf;                                 \
            pf.u[0] = pk2(v0.x, v0.y); pf.u[1] = pk2(v0.z, v0.w);                      \
            pf.u[2] = pk2(v1.x, v1.y); pf.u[3] = pk2(v1.z, v1.w);                      \
            *(frag16*)&Asl[BUF][(w * 2 + j) * 512 + lane * 8] = pf.f;                  \
        } else {                                                                       \
            __builtin_amdgcn_global_load_lds(                                          \
                AS1(Ab + (size_t)(bm + rSA[j]) * K + (K1) + cSA[j] * 8),               \
                AS3(&Asl[BUF][(w * 2 + j) * 512]), 16, 0, 0);                          \
        }                                                                              \
    }

    STAGE_A(0, 0);
    #pragma unroll
    for (int j = 0; j < 4; j++)
        __builtin_amdgcn_global_load_lds(AS1(W + (size_t)rSB[j] * K + cSB[j] * 8),
                                         AS3(&Bsl[0][(w * 4 + j) * 512]), 16, 0, 0);

    for (int kk = 0; kk < nK; kk++) {
        const int cur = kk & 1;
        __syncthreads();
        if (kk + 1 < nK) {
            const int k1 = (kk + 1) * 64;
            STAGE_A(k1, cur ^ 1);
            #pragma unroll
            for (int j = 0; j < 4; j++)
                __builtin_amdgcn_global_load_lds(AS1(W + (size_t)rSB[j] * K + k1 + cSB[j] * 8),
                                                 AS3(&Bsl[cur ^ 1][(w * 4 + j) * 512]), 16, 0, 0);
        }
        #pragma unroll
        for (int ks = 0; ks < 2; ks++) {
            frag16 af[4], bf[2];
            #pragma unroll
            for (int mt = 0; mt < 4; mt++) {
                int r = mt * 16 + l16;
                af[mt] = *(const frag16*)&Asl[cur][r * 64 + (((ks * 4 + quad) ^ (r & 7)) * 8)];
            }
            #pragma unroll
            for (int nt = 0; nt < 2; nt++) {
                int r = w * 32 + nt * 16 + l16;
                bf[nt] = *(const frag16*)&Bsl[cur][r * 64 + (((ks * 4 + quad) ^ (r & 7)) * 8)];
            }
            #pragma unroll
            for (int mt = 0; mt < 4; mt++)
                #pragma unroll
                for (int nt = 0; nt < 2; nt++)
                    acc[mt][nt] = __builtin_amdgcn_mfma_f32_16x16x32_bf16(af[mt], bf[nt], acc[mt][nt], 0, 0, 0);
        }
    }
#undef STAGE_A
    #pragma unroll
    for (int mt = 0; mt < 4; mt++) {
        #pragma unroll
        for (int reg = 0; reg < 4; reg++) {
            int row = bm + mt * 16 + quad * 4 + reg;
            #pragma unroll
            for (int nt = 0; nt < 2; nt++) {
                int col = bn + w * 32 + nt * 16 + l16;
                if (col < N) {
                    if constexpr (BF16OUT)
                        ((__hip_bfloat16*)Cv)[(size_t)row * N + col] = __float2bfloat16(acc[mt][nt][reg]);
                    else
                        ((float*)Cv)[(size_t)row * N + col] = acc[mt][nt][reg];
                }
            }
        }
    }
}

// ---------------- RoPE + rank contraction, 4 tokens/block ----------
// Reads bf16 abqkv (packed 2xbf16 = 4B/lane loads), stages fp32 in LDS.
__global__ __launch_bounds__(256) void qkv_kernel(
    const __hip_bfloat16* __restrict__ ab,
    __hip_bfloat16* __restrict__ q, __hip_bfloat16* __restrict__ k,
    __hip_bfloat16* __restrict__ vT)
{
    const int tok0 = blockIdx.x * 4;
    const int w = threadIdx.x >> 6;
    const int d = threadIdx.x & 63;
    const int token = tok0 + w;
    const int b = token / TT;
    const int t = token % TT;
    __shared__ float sab[4][NQK];
    __shared__ __align__(8) __hip_bfloat16 vbuf[NHEADS][DHEAD][4];
    const __hip_bfloat16* aq = ab + (size_t)token * NQK;
    #pragma unroll
    for (int i2 = d; i2 < NQK / 2; i2 += 64) {
        unsigned int u = *(const unsigned int*)&aq[i2 * 2];
        sab[w][i2 * 2 + 0] = bfu2f((unsigned short)(u & 0xffff));
        sab[w][i2 * 2 + 1] = bfu2f((unsigned short)(u >> 16));
    }
    const float* sq  = sab[w];
    const float* skv = sab[w] + 480;
    const int i32 = d & 31;
    // 10000^(-i/32) = 2^(-i/32 * log2(10000))
    float inv_freq = exp2_hw(-(float)i32 * (13.287712379549449f / 32.0f));
    float fr = (float)t * inv_freq;
    float c = cosf(fr), s = sinf(fr);
    __syncthreads();
    float rot[4];
    #pragma unroll
    for (int r = 0; r < 4; r++) {
        float x1 = skv[r * CHDIM + NHEADS + i32];
        float x2 = skv[r * CHDIM + NHEADS + 32 + i32];
        rot[r] = (d < 32) ? (x1 * c + x2 * s) : (-x1 * s + x2 * c);
    }
    float bqv[RQn];
    #pragma unroll
    for (int r = 0; r < RQn; r++) bqv[r] = sq[r * CHDIM + NHEADS + d];
    #pragma unroll
    for (int h = 0; h < NHEADS; h++) {
        float accq = 0.0f;
        #pragma unroll
        for (int r = 0; r < RQn; r++)
            accq += sq[r * CHDIM + h] * bqv[r];
        // q-scale: 1/sqrt(64)/RQ with log2(e) folded in (flash uses 2^x).
        q[((size_t)(b * NHEADS + h) * TT + t) * DHEAD + d] =
            __float2bfloat16(accq * (0.125f / 6.0f) * 1.4426950408889634f);
        float acck = 0.0f, accv = 0.0f;
        #pragma unroll
        for (int r = 0; r < RKn; r++)
            acck += skv[r * CHDIM + h] * rot[r];
        #pragma unroll
        for (int r = 0; r < RVn; r++)
            accv += skv[(RKn + r) * CHDIM + h] * rot[RKn + r];
        k[((size_t)(b * NHEADS + h) * TT + t) * DHEAD + d] = __float2bfloat16(acck * 0.5f);
        vbuf[h][d][w] = __float2bfloat16(accv * 0.5f);
    }
    __syncthreads();
    const int t0 = tok0 % TT;
    const int b0 = tok0 / TT;
    for (int row = threadIdx.x; row < NHEADS * DHEAD; row += 256) {
        int h = row >> 6, dd = row & 63;
        *(uint2*)&vT[((size_t)(b0 * NHEADS + h) * DHEAD + dd) * TT + t0] =
            *(const uint2*)&vbuf[h][dd][0];
    }
}

// -------- P^T B-frag construction from exp'd S registers (shared helper) ----
// __builtin_amdgcn_permlane32_swap(A,B,fi,bc) -> {A',B'} where
//   A' = {A.lo lanes 0-31, B.lo delivered to lanes 32-63}
//   B' = {A.hi delivered to lanes 0-31, B.hi lanes 32-63}
static __device__ __forceinline__ void build_pfrag(
    const float* s0, const float* s1, frag16 Pf[4])
{
    #pragma unroll
    for (int k2 = 0; k2 < 4; k2++) {
        const float* sF = (k2 >= 2) ? s1 : s0;
        const int bs = 8 * (k2 & 1);
        unsigned int a0 = pk2(sF[bs + 0], sF[bs + 1]);
        unsigned int b0 = pk2(sF[bs + 2], sF[bs + 3]);
        unsigned int a1 = pk2(sF[bs + 4], sF[bs + 5]);
        unsigned int b1 = pk2(sF[bs + 6], sF[bs + 7]);
        uint2v ra = __builtin_amdgcn_permlane32_swap(a0, a1, false, false);
        uint2v rb = __builtin_amdgcn_permlane32_swap(b0, b1, false, false);
        union { frag16 f; unsigned int u[4]; } pf;
        pf.u[0] = ra[0]; pf.u[1] = rb[0]; pf.u[2] = ra[1]; pf.u[3] = rb[1];
        Pf[k2] = pf.f;
    }
}

// ---------------- single attention tile (LDS operands, XOR-swizzled) --------
static __device__ __forceinline__ void attn_tile(
    const __hip_bfloat16* __restrict__ Kc, const __hip_bfloat16* __restrict__ Vc,
    const frag16 qB[4], f32x16& O0, f32x16& O1, float& lpart,
    const int l31, const int hi, const int xi,
    const bool domask, const int kb0, const int qlane)
{
    f32x16 ST0 = {}, ST1 = {};
    __builtin_amdgcn_s_setprio(1);
    #pragma unroll
    for (int kt4 = 0; kt4 < 4; kt4++) {
        int c8 = kt4 * 2 + hi;
        frag16 kf0 = *(const frag16*)&Kc[l31 * 64 + ((c8 ^ xi) * 8)];
        frag16 kf1 = *(const frag16*)&Kc[(32 + l31) * 64 + ((c8 ^ xi) * 8)];
        ST0 = __builtin_amdgcn_mfma_f32_32x32x16_bf16(kf0, qB[kt4], ST0, 0, 0, 0);
        ST1 = __builtin_amdgcn_mfma_f32_32x32x16_bf16(kf1, qB[kt4], ST1, 0, 0, 0);
    }
    __builtin_amdgcn_s_setprio(0);
    float* s0 = (float*)&ST0;
    float* s1 = (float*)&ST1;
    if (domask) {
        int kbq = kb0 + 4 * hi;
        #pragma unroll
        for (int reg = 0; reg < 16; reg++) {
            int rowc = (reg & 3) + 8 * (reg >> 2);
            if (kbq + rowc > qlane)      s0[reg] = -1e30f;
            if (kbq + 32 + rowc > qlane) s1[reg] = -1e30f;
        }
    }
    #pragma unroll
    for (int reg = 0; reg < 16; reg++) {
        float p0 = exp2_hw(s0[reg]);
        float p1 = exp2_hw(s1[reg]);
        s0[reg] = p0; s1[reg] = p1;
        lpart += p0 + p1;
    }
    frag16 Pf[4];
    build_pfrag(s0, s1, Pf);
    __builtin_amdgcn_s_setprio(1);
    #pragma unroll
    for (int k2 = 0; k2 < 4; k2++) {
        int c8 = k2 * 2 + hi;
        frag16 vf0 = *(const frag16*)&Vc[l31 * 64 + ((c8 ^ xi) * 8)];
        frag16 vf1 = *(const frag16*)&Vc[(32 + l31) * 64 + ((c8 ^ xi) * 8)];
        O0 = __builtin_amdgcn_mfma_f32_32x32x16_bf16(vf0, Pf[k2], O0, 0, 0, 0);
        O1 = __builtin_amdgcn_mfma_f32_32x32x16_bf16(vf1, Pf[k2], O1, 0, 0, 0);
    }
    __builtin_amdgcn_s_setprio(0);
}

// ------- fused split-K causal flash attention, 512-thread blocks ------------
// R9 exact (best measured: 157.8us total). Block = (bh, qt): 8 waves.
// Waves 0-3 = K-half 0 [0,qt+1), waves 4-7 = K-half 1 [qt+1, 2qt+2).
// Per-half dbuf staging (64KB LDS -> 2 blocks/CU = 16 waves/CU); both halves
// run identical nst=qt+1 step counts -> per-step barriers align. Epilogue:
// part-1 waves drop O/l into LDS (over dead staging, pad-33 = conflict-free);
// part-0 adds, normalizes with full row-sum, writes y bf16 directly.
// Balance: Bid c / c+256 carry complementary qt (15-x / x).
// XCD pinning (T1): Bid&7 = XCD, 4 bh/XCD -> 2MB K/V set in 4MB L2.
__global__ __launch_bounds__(512, 4) void flash_mfma(
    const __hip_bfloat16* __restrict__ q, const __hip_bfloat16* __restrict__ k,
    const __hip_bfloat16* __restrict__ vT, __hip_bfloat16* __restrict__ y)
{
    const int Bid = blockIdx.x;          // 512
    const int m = Bid & 255;
    const int half = Bid >> 8;
    const int xcd = m & 7;
    const int bh  = xcd * 4 + ((m >> 3) & 3);
    const int qx  = m >> 5;              // 0..7
    const int qt  = half ? qx : (15 - qx);
    const int nst = qt + 1;

    const int tid = threadIdx.x;
    const int w8 = tid >> 6;             // 0..7
    const int part = w8 >> 2;
    const int w = w8 & 3;
    const int lane = tid & 63;
    const int l31 = lane & 31;
    const int hi = lane >> 5;
    const int xi = l31 & 7;
    const int paddr = (lane ^ 32) << 2;
    const int k0 = part * nst;

    __shared__ __align__(16) char smem[65536];
    __hip_bfloat16* Ks = (__hip_bfloat16*)(smem + part * 32768);           // [2][4096]
    __hip_bfloat16* Vs = (__hip_bfloat16*)(smem + part * 32768 + 16384);   // [2][4096]

    const size_t base = (size_t)bh * TT * DHEAD;
    const __hip_bfloat16* qb = q + base;
    const __hip_bfloat16* kb = k + base;
    const __hip_bfloat16* vb = vT + base;

    const int ktd = 2 * qt + (w >> 1);           // this wave's diagonal tile
    const int qlane = qt * 128 + w * 32 + l31;   // this lane's q row

    int offK[2], offV[2];
    #pragma unroll
    for (int j = 0; j < 2; j++) {
        int Lc = w * 128 + j * 64 + lane;
        int r = Lc >> 3, c8 = Lc & 7, g8 = c8 ^ (r & 7);
        offK[j] = r * 64 + g8 * 8;
        offV[j] = r * TT + g8 * 8;
    }

    frag16 qB[4];
    #pragma unroll
    for (int kt4 = 0; kt4 < 4; kt4++)
        qB[kt4] = *(const frag16*)&qb[(size_t)qlane * DHEAD + kt4 * 16 + hi * 8];

    f32x16 O0 = {}, O1 = {};
    float l = 0.0f;

    #pragma unroll
    for (int j = 0; j < 2; j++) {
        __builtin_amdgcn_global_load_lds(AS1(kb + (size_t)k0 * 4096 + offK[j]),
                                         AS3(&Ks[w * 1024 + j * 512]), 16, 0, 0);
        __builtin_amdgcn_global_load_lds(AS1(vb + (size_t)k0 * 64 + offV[j]),
                                         AS3(&Vs[w * 1024 + j * 512]), 16, 0, 0);
    }

    for (int kt = 0; kt < nst; kt++) {
        const int cur = kt & 1;
        __syncthreads();
        if (kt + 1 < nst) {
            const int phys1 = k0 + kt + 1;
            #pragma unroll
            for (int j = 0; j < 2; j++) {
                __builtin_amdgcn_global_load_lds(AS1(kb + (size_t)phys1 * 4096 + offK[j]),
                                                 AS3(&Ks[(cur ^ 1) * 4096 + w * 1024 + j * 512]), 16, 0, 0);
                __builtin_amdgcn_global_load_lds(AS1(vb + (size_t)phys1 * 64 + offV[j]),
                                                 AS3(&Vs[(cur ^ 1) * 4096 + w * 1024 + j * 512]), 16, 0, 0);
            }
        }
        const int phys = k0 + kt;
        if (phys <= ktd)
            attn_tile(Ks + cur * 4096, Vs + cur * 4096, qB, O0, O1, l,
                      l31, hi, xi, phys == ktd, phys * 64, qlane);
    }

    // ---- in-block combine: part1 -> LDS (over dead staging), part0 adds ----
    __syncthreads();                       // all staging reads complete
    float* Oex = (float*)smem;             // 4 pairs x 64 lanes x 33 floats
    float* lex = (float*)(smem + 33792);   // 4 x 64 floats
    float* o0 = (float*)&O0;
    float* o1 = (float*)&O1;
    if (part == 1) {
        float* dst = Oex + (w * 64 + lane) * 33;
        #pragma unroll
        for (int i = 0; i < 16; i++) { dst[i] = o0[i]; dst[16 + i] = o1[i]; }
        lex[w * 64 + lane] = l;
    }
    __syncthreads();
    if (part == 0) {
        const float* src = Oex + (w * 64 + lane) * 33;
        #pragma unroll
        for (int i = 0; i < 16; i++) { o0[i] += src[i]; o1[i] += src[16 + i]; }
        l += lex[w * 64 + lane];
        float lother = __int_as_float(__builtin_amdgcn_ds_bpermute(paddr, __float_as_int(l)));
        float inv = 1.0f / (l + lother);
        const int b = bh >> 4, h = bh & 15;
        __hip_bfloat16* yp = y + ((size_t)(b * TT + qlane)) * DDim + h * DHEAD;
        #pragma unroll
        for (int gg = 0; gg < 4; gg++) {
            int d0 = 8 * gg + 4 * hi;
            uint2 pa, pb;
            pa.x = pk2(o0[4*gg+0] * inv, o0[4*gg+1] * inv);
            pa.y = pk2(o0[4*gg+2] * inv, o0[4*gg+3] * inv);
            pb.x = pk2(o1[4*gg+0] * inv, o1[4*gg+1] * inv);
            pb.y = pk2(o1[4*gg+2] * inv, o1[4*gg+3] * inv);
            *(uint2*)&yp[d0] = pa;
            *(uint2*)&yp[32 + d0] = pb;
        }
    }
}

extern "C" void kernel_launch(void* const* d_in, const int* in_sizes, int n_in,
                              void* d_out, int out_size, void* d_ws, size_t ws_size,
                              hipStream_t stream) {
    const float* x      = (const float*)d_in[0];
    const float* W_abq  = (const float*)d_in[1];
    const float* W_abkv = (const float*)d_in[2];
    const float* W_o    = (const float*)d_in[3];
    float* out = (float*)d_out;

    char* ws = (char*)d_ws;
    __hip_bfloat16* wqk  = (__hip_bfloat16*)ws;  ws += (size_t)NQK * 1024 * 2;
    __hip_bfloat16* wo_b = (__hip_bfloat16*)ws;  ws += (size_t)1048576 * 2;
    __hip_bfloat16* abqkv = (__hip_bfloat16*)ws; ws += (size_t)4096 * NQK * 2;
    __hip_bfloat16* qb = (__hip_bfloat16*)ws;    ws += (size_t)4194304 * 2;
    __hip_bfloat16* kb = (__hip_bfloat16*)ws;    ws += (size_t)4194304 * 2;
    __hip_bfloat16* vT = (__hip_bfloat16*)ws;    ws += (size_t)4194304 * 2;
    __hip_bfloat16* yb = (__hip_bfloat16*)ws;    ws += (size_t)4194304 * 2;

    cvt_w<<<dim3(1824), dim3(256), 0, stream>>>(W_abq, W_abkv, W_o, wqk, wo_b);
    gemm_bf16<true, true><<<dim3(7, 64), dim3(256), 0, stream>>>(x, wqk, abqkv, 4096, NQK, 1024);
    qkv_kernel<<<dim3(1024), dim3(256), 0, stream>>>(abqkv, qb, kb, vT);
    flash_mfma<<<dim3(512), dim3(512), 0, stream>>>(qb, kb, vT, yb);
    gemm_bf16<false, false><<<dim3(8, 64), dim3(256), 0, stream>>>(yb, wo_b, out, 4096, 1024, 1024);
}